// Round 2
// baseline (18417.313 us; speedup 1.0000x reference)
//
#include <hip/hip_runtime.h>
#include <stdint.h>

#define BB 64
#define TT 512
#define EE 512
#define HH 1024
#define GG 4096

#define NA0 64
#define NL0 128
#define NA1 128
#define NL1 128
#define NWG (NA0 + NL0 + NA1 + NL1)

#define XP0_SLOTS 8

typedef short v8b __attribute__((ext_vector_type(8)));
typedef float v4f __attribute__((ext_vector_type(4)));
typedef unsigned short u16;
typedef unsigned int u32;

__device__ __forceinline__ u16 f2bf(float f) {
  union { float f; u32 i; } v; v.f = f;
  u32 u = v.i;
  u32 r = (u + 0x7FFFu + ((u >> 16) & 1u)) >> 16;
  return (u16)r;
}
__device__ __forceinline__ float sigm(float x) { return 1.0f / (1.0f + __expf(-x)); }

// ---------------- prep: gather embeddings (fp32 -> bf16), zero flags + h rings, lens ----------
__global__ void prep_kernel(const int* __restrict__ x, const float* __restrict__ emb,
                            u16* __restrict__ e16, u16* __restrict__ h0r, u16* __restrict__ h1r,
                            int* __restrict__ lens, u32* flags, int flag_u32s) {
  long stride = (long)gridDim.x * blockDim.x;
  long gid = (long)blockIdx.x * blockDim.x + threadIdx.x;
  const long totalE = (long)BB * TT * EE;
  for (long i = gid; i < totalE; i += stride) {
    int d = (int)(i % EE);
    long bt = i / EE;  // b*T + t
    int tok = x[bt];
    e16[i] = f2bf(emb[(long)tok * EE + d]);
  }
  for (long i = gid; i < (long)flag_u32s; i += stride) flags[i] = 0u;
  const long ringN = 4L * BB * HH;
  for (long i = gid; i < ringN; i += stride) { h0r[i] = 0; h1r[i] = 0; }
  int gwave = (int)(gid >> 6);
  int lane = (int)(gid & 63);
  if (gwave < BB) {
    int cnt = 0;
    for (int t2 = lane; t2 < TT; t2 += 64) cnt += (x[gwave * TT + t2] == 0) ? 1 : 0;
    for (int off = 32; off; off >>= 1) cnt += __shfl_down(cnt, off, 64);
    if (lane == 0) lens[gwave] = TT - cnt;
  }
}

// ---------------- flag helpers ----------------
__device__ __forceinline__ void wait_set(u32* f, int n) {
  for (int i = threadIdx.x; i < n; i += 256) {
    while (__hip_atomic_load(&f[i], __ATOMIC_RELAXED, __HIP_MEMORY_SCOPE_AGENT) == 0u)
      __builtin_amdgcn_s_sleep(2);
  }
}

// ---------------- persistent pipeline kernel ----------------
__global__ __launch_bounds__(256, 2) void lstm_persist(
    const u16* __restrict__ e16,
    const float* __restrict__ Wih0, const float* __restrict__ Whh0, const float* __restrict__ b0,
    const float* __restrict__ Wih1, const float* __restrict__ Whh1, const float* __restrict__ b1,
    const int* __restrict__ lens,
    float* __restrict__ xp0, float* __restrict__ xp1,
    u16* __restrict__ h0r, u16* __restrict__ h1r,
    float* __restrict__ lasth,
    u32* fA0, u32* fL0, u32* fA1, u32* fL1) {
  __shared__ __align__(16) short Wlds[32768];  // 64 KB weight slice, [K/8][rows][8] bf16
  const int wg = blockIdx.x;
  const int tid = threadIdx.x;
  const int wave = tid >> 6;
  const int lane = tid & 63;
  const int m16 = lane & 15;
  const int q = lane >> 4;
  const int bm = wave * 16 + m16;    // A-frag batch row (M dim)
  const int bq = wave * 16 + q * 4;  // C-tile batch base for this lane (M = quad*4+reg)

  if (wg < NA0) {
    // ================= A0: xp0[t] = W_ih0 @ e_t + b0  (rows rbase..rbase+63, K=512) ==========
    const int rbase = wg * 64;
    for (int c2 = tid; c2 < 64 * 64; c2 += 256) {
      int r = c2 >> 6, kb = c2 & 63;
      const float* src = Wih0 + (long)(rbase + r) * EE + kb * 8;
      v8b w;
#pragma unroll
      for (int j = 0; j < 8; ++j) w[j] = (short)f2bf(src[j]);
      *(v8b*)&Wlds[(kb * 64 + r) * 8] = w;
    }
    __syncthreads();
    float bias[4];
#pragma unroll
    for (int nt = 0; nt < 4; ++nt) bias[nt] = b0[rbase + nt * 16 + m16];
    for (int t = 0; t < TT; ++t) {
      if (t >= XP0_SLOTS) wait_set(fL0 + (t - XP0_SLOTS) * NL0, NL0);  // ring back-pressure
      __syncthreads();
      __builtin_amdgcn_fence(__ATOMIC_ACQUIRE, "agent");
      v4f acc[4] = {{0.f,0.f,0.f,0.f},{0.f,0.f,0.f,0.f},{0.f,0.f,0.f,0.f},{0.f,0.f,0.f,0.f}};
      const u16* ap = e16 + (long)bm * (TT * EE) + (long)t * EE + q * 8;
#pragma unroll 4
      for (int k0 = 0; k0 < EE; k0 += 32) {
        v8b a = *(const v8b*)(ap + k0);
#pragma unroll
        for (int nt = 0; nt < 4; ++nt) {
          v8b w = *(const v8b*)&Wlds[(((k0 >> 3) + q) * 64 + nt * 16 + m16) * 8];
          acc[nt] = __builtin_amdgcn_mfma_f32_16x16x32_bf16(a, w, acc[nt], 0, 0, 0);
        }
      }
      const int slot = t & (XP0_SLOTS - 1);
#pragma unroll
      for (int nt = 0; nt < 4; ++nt) {
        int n = rbase + nt * 16 + m16;
        v4f v = acc[nt] + bias[nt];
        *(v4f*)&xp0[(long)slot * (GG * BB) + (long)n * BB + bq] = v;
      }
      __syncthreads();
      if (tid == 0)
        __hip_atomic_store(&fA0[t * NA0 + wg], 1u, __ATOMIC_RELEASE, __HIP_MEMORY_SCOPE_AGENT);
    }
  } else if (wg < NA0 + NL0) {
    // ================= L0: gates = xp0 + W_hh0 @ h0[t-1]; cell update (8 units) ==============
    const int uwg = wg - NA0;
    const int ubase = uwg * 8;
    for (int c2 = tid; c2 < 32 * 128; c2 += 256) {
      int r = c2 >> 7, kb = c2 & 127;
      int grow = (r >> 3) * HH + ubase + (r & 7);  // rows ordered [i0..7|f0..7|g0..7|o0..7]
      const float* src = Whh0 + (long)grow * HH + kb * 8;
      v8b w;
#pragma unroll
      for (int j = 0; j < 8; ++j) w[j] = (short)f2bf(src[j]);
      *(v8b*)&Wlds[(kb * 32 + r) * 8] = w;
    }
    __syncthreads();
    const int gi0 = (m16 >> 3);
    const int j0 = m16 & 7;
    const int row0 = gi0 * HH + ubase + j0;        // i (m16<8) or f
    const int row1 = (2 + gi0) * HH + ubase + j0;  // g (m16<8) or o
    const bool lo = (m16 < 8);
    float cst[4] = {0.f, 0.f, 0.f, 0.f};
    for (int t = 0; t < TT; ++t) {
      wait_set(fA0 + t * NA0, NA0);
      if (t >= 1) wait_set(fL0 + (t - 1) * NL0, NL0);
      if (t >= 4) wait_set(fA1 + (t - 4) * NA1, NA1);  // h0 ring back-pressure
      __syncthreads();
      __builtin_amdgcn_fence(__ATOMIC_ACQUIRE, "agent");
      const u16* hp = h0r + ((t + 3) & 3) * (BB * HH) + bm * HH + q * 8;
      v4f acc0 = {0.f,0.f,0.f,0.f}, acc1 = {0.f,0.f,0.f,0.f};
#pragma unroll 4
      for (int k0 = 0; k0 < HH; k0 += 32) {
        v8b a = *(const v8b*)(hp + k0);
        v8b w0 = *(const v8b*)&Wlds[(((k0 >> 3) + q) * 32 + m16) * 8];
        v8b w1 = *(const v8b*)&Wlds[(((k0 >> 3) + q) * 32 + 16 + m16) * 8];
        acc0 = __builtin_amdgcn_mfma_f32_16x16x32_bf16(a, w0, acc0, 0, 0, 0);
        acc1 = __builtin_amdgcn_mfma_f32_16x16x32_bf16(a, w1, acc1, 0, 0, 0);
      }
      const float* xpS = xp0 + (long)(t & (XP0_SLOTS - 1)) * (GG * BB);
      v4f x0 = *(const v4f*)&xpS[(long)row0 * BB + bq];
      v4f x1 = *(const v4f*)&xpS[(long)row1 * BB + bq];
      acc0 += x0; acc1 += x1;
      u16* hw = h0r + (t & 3) * (BB * HH);
#pragma unroll
      for (int r = 0; r < 4; ++r) {
        float a0 = acc0[r], a1 = acc1[r];
        float p0 = __shfl_xor(a0, 8, 64);
        float p1 = __shfl_xor(a1, 8, 64);
        float iv = lo ? a0 : p0;
        float fv = lo ? p0 : a0;
        float gv = lo ? a1 : p1;
        float ov = lo ? p1 : a1;
        float cn = sigm(fv) * cst[r] + sigm(iv) * tanhf(gv);
        cst[r] = cn;
        float hv = sigm(ov) * tanhf(cn);
        if (lo) hw[(bq + r) * HH + ubase + j0] = f2bf(hv);
      }
      __syncthreads();
      if (tid == 0)
        __hip_atomic_store(&fL0[t * NL0 + uwg], 1u, __ATOMIC_RELEASE, __HIP_MEMORY_SCOPE_AGENT);
    }
  } else if (wg < NA0 + NL0 + NA1) {
    // ================= A1: xp1[t] = W_ih1 @ h0[t] + b1 (rows rbase..rbase+31, K=1024) ========
    const int awg = wg - (NA0 + NL0);
    const int rbase = awg * 32;
    for (int c2 = tid; c2 < 32 * 128; c2 += 256) {
      int r = c2 >> 7, kb = c2 & 127;
      const float* src = Wih1 + (long)(rbase + r) * HH + kb * 8;
      v8b w;
#pragma unroll
      for (int j = 0; j < 8; ++j) w[j] = (short)f2bf(src[j]);
      *(v8b*)&Wlds[(kb * 32 + r) * 8] = w;
    }
    __syncthreads();
    float bias[2];
#pragma unroll
    for (int nt = 0; nt < 2; ++nt) bias[nt] = b1[rbase + nt * 16 + m16];
    for (int t = 0; t < TT; ++t) {
      wait_set(fL0 + t * NL0, NL0);
      if (t >= 4) wait_set(fL1 + (t - 4) * NL1, NL1);  // xp1 ring back-pressure
      __syncthreads();
      __builtin_amdgcn_fence(__ATOMIC_ACQUIRE, "agent");
      const u16* hp = h0r + (t & 3) * (BB * HH) + bm * HH + q * 8;
      v4f acc0 = {0.f,0.f,0.f,0.f}, acc1 = {0.f,0.f,0.f,0.f};
#pragma unroll 4
      for (int k0 = 0; k0 < HH; k0 += 32) {
        v8b a = *(const v8b*)(hp + k0);
        v8b w0 = *(const v8b*)&Wlds[(((k0 >> 3) + q) * 32 + m16) * 8];
        v8b w1 = *(const v8b*)&Wlds[(((k0 >> 3) + q) * 32 + 16 + m16) * 8];
        acc0 = __builtin_amdgcn_mfma_f32_16x16x32_bf16(a, w0, acc0, 0, 0, 0);
        acc1 = __builtin_amdgcn_mfma_f32_16x16x32_bf16(a, w1, acc1, 0, 0, 0);
      }
      const int slot = t & 3;
      v4f v0 = acc0 + bias[0];
      v4f v1 = acc1 + bias[1];
      *(v4f*)&xp1[(long)slot * (GG * BB) + (long)(rbase + m16) * BB + bq] = v0;
      *(v4f*)&xp1[(long)slot * (GG * BB) + (long)(rbase + 16 + m16) * BB + bq] = v1;
      __syncthreads();
      if (tid == 0)
        __hip_atomic_store(&fA1[t * NA1 + awg], 1u, __ATOMIC_RELEASE, __HIP_MEMORY_SCOPE_AGENT);
    }
  } else {
    // ================= L1: gates = xp1 + W_hh1 @ h1[t-1]; cell + last-step capture ============
    const int uwg = wg - (NA0 + NL0 + NA1);
    const int ubase = uwg * 8;
    for (int c2 = tid; c2 < 32 * 128; c2 += 256) {
      int r = c2 >> 7, kb = c2 & 127;
      int grow = (r >> 3) * HH + ubase + (r & 7);
      const float* src = Whh1 + (long)grow * HH + kb * 8;
      v8b w;
#pragma unroll
      for (int j = 0; j < 8; ++j) w[j] = (short)f2bf(src[j]);
      *(v8b*)&Wlds[(kb * 32 + r) * 8] = w;
    }
    __syncthreads();
    const int gi0 = (m16 >> 3);
    const int j0 = m16 & 7;
    const int row0 = gi0 * HH + ubase + j0;
    const int row1 = (2 + gi0) * HH + ubase + j0;
    const bool lo = (m16 < 8);
    float cst[4] = {0.f, 0.f, 0.f, 0.f};
    int len4[4];
#pragma unroll
    for (int r = 0; r < 4; ++r) len4[r] = lens[bq + r];
    for (int t = 0; t < TT; ++t) {
      wait_set(fA1 + t * NA1, NA1);
      if (t >= 1) wait_set(fL1 + (t - 1) * NL1, NL1);
      __syncthreads();
      __builtin_amdgcn_fence(__ATOMIC_ACQUIRE, "agent");
      const u16* hp = h1r + ((t + 3) & 3) * (BB * HH) + bm * HH + q * 8;
      v4f acc0 = {0.f,0.f,0.f,0.f}, acc1 = {0.f,0.f,0.f,0.f};
#pragma unroll 4
      for (int k0 = 0; k0 < HH; k0 += 32) {
        v8b a = *(const v8b*)(hp + k0);
        v8b w0 = *(const v8b*)&Wlds[(((k0 >> 3) + q) * 32 + m16) * 8];
        v8b w1 = *(const v8b*)&Wlds[(((k0 >> 3) + q) * 32 + 16 + m16) * 8];
        acc0 = __builtin_amdgcn_mfma_f32_16x16x32_bf16(a, w0, acc0, 0, 0, 0);
        acc1 = __builtin_amdgcn_mfma_f32_16x16x32_bf16(a, w1, acc1, 0, 0, 0);
      }
      const float* xpS = xp1 + (long)(t & 3) * (GG * BB);
      v4f x0 = *(const v4f*)&xpS[(long)row0 * BB + bq];
      v4f x1 = *(const v4f*)&xpS[(long)row1 * BB + bq];
      acc0 += x0; acc1 += x1;
      u16* hw = h1r + (t & 3) * (BB * HH);
#pragma unroll
      for (int r = 0; r < 4; ++r) {
        float a0 = acc0[r], a1 = acc1[r];
        float p0 = __shfl_xor(a0, 8, 64);
        float p1 = __shfl_xor(a1, 8, 64);
        float iv = lo ? a0 : p0;
        float fv = lo ? p0 : a0;
        float gv = lo ? a1 : p1;
        float ov = lo ? p1 : a1;
        float cn = sigm(fv) * cst[r] + sigm(iv) * tanhf(gv);
        cst[r] = cn;
        float hv = sigm(ov) * tanhf(cn);
        if (lo) {
          hw[(bq + r) * HH + ubase + j0] = f2bf(hv);
          if (t == len4[r] - 1) lasth[(long)(bq + r) * HH + ubase + j0] = hv;
        }
      }
      __syncthreads();
      if (tid == 0)
        __hip_atomic_store(&fL1[t * NL1 + uwg], 1u, __ATOMIC_RELEASE, __HIP_MEMORY_SCOPE_AGENT);
    }
  }
}

// ---------------- final: out = last_h1 @ W_out^T + b_out (all fp32) ----------------
__global__ void out_kernel(const float* __restrict__ lasth, const float* __restrict__ Wout,
                           const float* __restrict__ bout, float* __restrict__ out) {
  int b = blockIdx.x;
  int k = threadIdx.x;
  if (k < 10) {
    float acc = bout[k];
    const float* hb = lasth + (long)b * HH;
    const float* wr = Wout + (long)k * HH;
    for (int j = 0; j < HH; ++j) acc += hb[j] * wr[j];
    out[b * 10 + k] = acc;
  }
}

extern "C" void kernel_launch(void* const* d_in, const int* in_sizes, int n_in,
                              void* d_out, int out_size, void* d_ws, size_t ws_size,
                              hipStream_t stream) {
  const int*   x    = (const int*)d_in[0];
  const float* emb  = (const float*)d_in[1];
  const float* Wih0 = (const float*)d_in[2];
  const float* Whh0 = (const float*)d_in[3];
  const float* b0   = (const float*)d_in[4];
  const float* Wih1 = (const float*)d_in[5];
  const float* Whh1 = (const float*)d_in[6];
  const float* b1   = (const float*)d_in[7];
  const float* Wout = (const float*)d_in[8];
  const float* bout = (const float*)d_in[9];

  char* ws = (char*)d_ws;
  u16*   e16   = (u16*)(ws + 0);            // 33,554,432 B
  float* xp0   = (float*)(ws + 33554432);   // 8 slots * 4096 * 64 * 4 = 8,388,608 B
  float* xp1   = (float*)(ws + 41943040);   // 4 slots * 4096 * 64 * 4 = 4,194,304 B
  u16*   h0r   = (u16*)(ws + 46137344);     // 4 slots * 64 * 1024 * 2 =   524,288 B
  u16*   h1r   = (u16*)(ws + 46661632);     //   524,288 B
  float* lasth = (float*)(ws + 47185920);   //   262,144 B
  int*   lens  = (int*)(ws + 47448064);     //       256 B
  u32*   flags = (u32*)(ws + 47448320);     //   917,504 B  (total ~46.2 MB)
  u32* fA0 = flags;
  u32* fL0 = fA0 + 512 * NA0;
  u32* fA1 = fL0 + 512 * NL0;
  u32* fL1 = fA1 + 512 * NA1;
  int flag_u32s = 512 * NA0 + 512 * NL0 + 512 * NA1 + 512 * NL1;

  prep_kernel<<<2048, 256, 0, stream>>>(x, emb, e16, h0r, h1r, lens, flags, flag_u32s);
  lstm_persist<<<NWG, 256, 0, stream>>>(e16, Wih0, Whh0, b0, Wih1, Whh1, b1, lens,
                                        xp0, xp1, h0r, h1r, lasth, fA0, fL0, fA1, fL1);
  out_kernel<<<BB, 64, 0, stream>>>(lasth, Wout, bout, (float*)d_out);
}

// Round 3
// 11172.728 us; speedup vs baseline: 1.6484x; 1.6484x over previous
//
#include <hip/hip_runtime.h>
#include <stdint.h>

#define BB 64
#define TT 512
#define EE 512
#define HH 1024
#define GG 4096

#define NA0 64
#define NL0 128
#define NA1 128
#define NL1 128
#define NWG (NA0 + NL0 + NA1 + NL1)

#define XP0_SLOTS 8

typedef short v8b __attribute__((ext_vector_type(8)));
typedef float v4f __attribute__((ext_vector_type(4)));
typedef unsigned short u16;
typedef unsigned int u32;
typedef unsigned long long u64;

__device__ __forceinline__ u16 f2bf(float f) {
  union { float f; u32 i; } v; v.f = f;
  u32 u = v.i;
  u32 r = (u + 0x7FFFu + ((u >> 16) & 1u)) >> 16;
  return (u16)r;
}
__device__ __forceinline__ float sigm(float x) { return 1.0f / (1.0f + __expf(-x)); }

// ---- cache-bypassing (agent-coherent, MALL-direct) accessors: sc0 sc1, no fences needed ----
__device__ __forceinline__ v8b ldg16_b(const u16* p) {
  union { v8b b; u64 q[2]; } u;
  u.q[0] = __hip_atomic_load((u64*)p,     __ATOMIC_RELAXED, __HIP_MEMORY_SCOPE_AGENT);
  u.q[1] = __hip_atomic_load((u64*)p + 1, __ATOMIC_RELAXED, __HIP_MEMORY_SCOPE_AGENT);
  return u.b;
}
__device__ __forceinline__ v4f ldg16_f(const float* p) {
  union { v4f f; u64 q[2]; } u;
  u.q[0] = __hip_atomic_load((u64*)p,     __ATOMIC_RELAXED, __HIP_MEMORY_SCOPE_AGENT);
  u.q[1] = __hip_atomic_load((u64*)p + 1, __ATOMIC_RELAXED, __HIP_MEMORY_SCOPE_AGENT);
  return u.f;
}
__device__ __forceinline__ void stg16_f(float* p, v4f v) {
  union { v4f f; u64 q[2]; } u; u.f = v;
  __hip_atomic_store((u64*)p,     u.q[0], __ATOMIC_RELAXED, __HIP_MEMORY_SCOPE_AGENT);
  __hip_atomic_store((u64*)p + 1, u.q[1], __ATOMIC_RELAXED, __HIP_MEMORY_SCOPE_AGENT);
}
__device__ __forceinline__ void stg2_h(u16* p, u16 v) {
  __hip_atomic_store(p, v, __ATOMIC_RELAXED, __HIP_MEMORY_SCOPE_AGENT);
}
// drain this wave's outstanding stores to the coherence point (MALL)
__device__ __forceinline__ void drain_stores() {
  asm volatile("s_waitcnt vmcnt(0)" ::: "memory");
}

// ---------------- prep: gather embeddings (fp32 -> bf16), zero flags + h rings, lens ----------
__global__ void prep_kernel(const int* __restrict__ x, const float* __restrict__ emb,
                            u16* __restrict__ e16, u16* __restrict__ h0r, u16* __restrict__ h1r,
                            int* __restrict__ lens, u32* flags, int flag_u32s) {
  long stride = (long)gridDim.x * blockDim.x;
  long gid = (long)blockIdx.x * blockDim.x + threadIdx.x;
  const long totalE = (long)BB * TT * EE;
  for (long i = gid; i < totalE; i += stride) {
    int d = (int)(i % EE);
    long bt = i / EE;  // b*T + t
    int tok = x[bt];
    e16[i] = f2bf(emb[(long)tok * EE + d]);
  }
  for (long i = gid; i < (long)flag_u32s; i += stride) flags[i] = 0u;
  const long ringN = 4L * BB * HH;
  for (long i = gid; i < ringN; i += stride) { h0r[i] = 0; h1r[i] = 0; }
  int gwave = (int)(gid >> 6);
  int lane = (int)(gid & 63);
  if (gwave < BB) {
    int cnt = 0;
    for (int t2 = lane; t2 < TT; t2 += 64) cnt += (x[gwave * TT + t2] == 0) ? 1 : 0;
    for (int off = 32; off; off >>= 1) cnt += __shfl_down(cnt, off, 64);
    if (lane == 0) lens[gwave] = TT - cnt;
  }
}

// ---------------- flag helpers ----------------
__device__ __forceinline__ void wait_set(u32* f, int n) {
  for (int i = threadIdx.x; i < n; i += 256) {
    while (__hip_atomic_load(&f[i], __ATOMIC_RELAXED, __HIP_MEMORY_SCOPE_AGENT) == 0u)
      __builtin_amdgcn_s_sleep(2);
  }
}
__device__ __forceinline__ void set_flag(u32* f) {
  // callers: all waves drained + __syncthreads'd before this
  if (threadIdx.x == 0)
    __hip_atomic_store(f, 1u, __ATOMIC_RELAXED, __HIP_MEMORY_SCOPE_AGENT);
}

// ---------------- persistent pipeline kernel ----------------
__global__ __launch_bounds__(256, 2) void lstm_persist(
    const u16* __restrict__ e16,
    const float* __restrict__ Wih0, const float* __restrict__ Whh0, const float* __restrict__ b0,
    const float* __restrict__ Wih1, const float* __restrict__ Whh1, const float* __restrict__ b1,
    const int* __restrict__ lens,
    float* __restrict__ xp0, float* __restrict__ xp1,
    u16* __restrict__ h0r, u16* __restrict__ h1r,
    float* __restrict__ lasth,
    u32* fA0, u32* fL0, u32* fA1, u32* fL1) {
  __shared__ __align__(16) short Wlds[32768];  // 64 KB weight slice, [K/8][rows][8] bf16
  const int wg = blockIdx.x;
  const int tid = threadIdx.x;
  const int wave = tid >> 6;
  const int lane = tid & 63;
  const int m16 = lane & 15;
  const int q = lane >> 4;
  const int bm = wave * 16 + m16;    // A-frag batch row (M dim)
  const int bq = wave * 16 + q * 4;  // C-tile batch base for this lane (M = quad*4+reg)

  if (wg < NA0) {
    // ================= A0: xp0[t] = W_ih0 @ e_t + b0  (rows rbase..rbase+63, K=512) ==========
    const int rbase = wg * 64;
    for (int c2 = tid; c2 < 64 * 64; c2 += 256) {
      int r = c2 >> 6, kb = c2 & 63;
      const float* src = Wih0 + (long)(rbase + r) * EE + kb * 8;
      v8b w;
#pragma unroll
      for (int j = 0; j < 8; ++j) w[j] = (short)f2bf(src[j]);
      *(v8b*)&Wlds[(kb * 64 + r) * 8] = w;
    }
    __syncthreads();
    float bias[4];
#pragma unroll
    for (int nt = 0; nt < 4; ++nt) bias[nt] = b0[rbase + nt * 16 + m16];
    for (int t = 0; t < TT; ++t) {
      if (t >= XP0_SLOTS) wait_set(fL0 + (t - XP0_SLOTS) * NL0, NL0);  // ring back-pressure
      __syncthreads();
      v4f acc[4] = {{0.f,0.f,0.f,0.f},{0.f,0.f,0.f,0.f},{0.f,0.f,0.f,0.f},{0.f,0.f,0.f,0.f}};
      const u16* ap = e16 + (long)bm * (TT * EE) + (long)t * EE + q * 8;
#pragma unroll 4
      for (int k0 = 0; k0 < EE; k0 += 32) {
        v8b a = *(const v8b*)(ap + k0);
#pragma unroll
        for (int nt = 0; nt < 4; ++nt) {
          v8b w = *(const v8b*)&Wlds[(((k0 >> 3) + q) * 64 + nt * 16 + m16) * 8];
          acc[nt] = __builtin_amdgcn_mfma_f32_16x16x32_bf16(a, w, acc[nt], 0, 0, 0);
        }
      }
      const int slot = t & (XP0_SLOTS - 1);
#pragma unroll
      for (int nt = 0; nt < 4; ++nt) {
        int n = rbase + nt * 16 + m16;
        v4f v = acc[nt] + bias[nt];
        stg16_f(&xp0[(long)slot * (GG * BB) + (long)n * BB + bq], v);
      }
      drain_stores();
      __syncthreads();
      set_flag(&fA0[t * NA0 + wg]);
    }
  } else if (wg < NA0 + NL0) {
    // ================= L0: gates = xp0 + W_hh0 @ h0[t-1]; cell update (8 units) ==============
    const int uwg = wg - NA0;
    const int ubase = uwg * 8;
    for (int c2 = tid; c2 < 32 * 128; c2 += 256) {
      int r = c2 >> 7, kb = c2 & 127;
      int grow = (r >> 3) * HH + ubase + (r & 7);  // rows ordered [i0..7|f0..7|g0..7|o0..7]
      const float* src = Whh0 + (long)grow * HH + kb * 8;
      v8b w;
#pragma unroll
      for (int j = 0; j < 8; ++j) w[j] = (short)f2bf(src[j]);
      *(v8b*)&Wlds[(kb * 32 + r) * 8] = w;
    }
    __syncthreads();
    const int gi0 = (m16 >> 3);
    const int j0 = m16 & 7;
    const int row0 = gi0 * HH + ubase + j0;        // i (m16<8) or f
    const int row1 = (2 + gi0) * HH + ubase + j0;  // g (m16<8) or o
    const bool lo = (m16 < 8);
    float cst[4] = {0.f, 0.f, 0.f, 0.f};
    for (int t = 0; t < TT; ++t) {
      wait_set(fA0 + t * NA0, NA0);
      if (t >= 1) wait_set(fL0 + (t - 1) * NL0, NL0);
      if (t >= 4) wait_set(fA1 + (t - 4) * NA1, NA1);  // h0 ring back-pressure
      __syncthreads();
      const float* xpS = xp0 + (long)(t & (XP0_SLOTS - 1)) * (GG * BB);
      v4f x0 = ldg16_f(&xpS[(long)row0 * BB + bq]);
      v4f x1 = ldg16_f(&xpS[(long)row1 * BB + bq]);
      const u16* hp = h0r + ((t + 3) & 3) * (BB * HH) + bm * HH + q * 8;
      v4f acc0 = {0.f,0.f,0.f,0.f}, acc1 = {0.f,0.f,0.f,0.f};
#pragma unroll 4
      for (int k0 = 0; k0 < HH; k0 += 32) {
        v8b a = ldg16_b(hp + k0);
        v8b w0 = *(const v8b*)&Wlds[(((k0 >> 3) + q) * 32 + m16) * 8];
        v8b w1 = *(const v8b*)&Wlds[(((k0 >> 3) + q) * 32 + 16 + m16) * 8];
        acc0 = __builtin_amdgcn_mfma_f32_16x16x32_bf16(a, w0, acc0, 0, 0, 0);
        acc1 = __builtin_amdgcn_mfma_f32_16x16x32_bf16(a, w1, acc1, 0, 0, 0);
      }
      acc0 += x0; acc1 += x1;
      u16* hw = h0r + (t & 3) * (BB * HH);
#pragma unroll
      for (int r = 0; r < 4; ++r) {
        float a0 = acc0[r], a1 = acc1[r];
        float p0 = __shfl_xor(a0, 8, 64);
        float p1 = __shfl_xor(a1, 8, 64);
        float iv = lo ? a0 : p0;
        float fv = lo ? p0 : a0;
        float gv = lo ? a1 : p1;
        float ov = lo ? p1 : a1;
        float cn = sigm(fv) * cst[r] + sigm(iv) * tanhf(gv);
        cst[r] = cn;
        float hv = sigm(ov) * tanhf(cn);
        if (lo) stg2_h(&hw[(bq + r) * HH + ubase + j0], f2bf(hv));
      }
      drain_stores();
      __syncthreads();
      set_flag(&fL0[t * NL0 + uwg]);
    }
  } else if (wg < NA0 + NL0 + NA1) {
    // ================= A1: xp1[t] = W_ih1 @ h0[t] + b1 (rows rbase..rbase+31, K=1024) ========
    const int awg = wg - (NA0 + NL0);
    const int rbase = awg * 32;
    for (int c2 = tid; c2 < 32 * 128; c2 += 256) {
      int r = c2 >> 7, kb = c2 & 127;
      const float* src = Wih1 + (long)(rbase + r) * HH + kb * 8;
      v8b w;
#pragma unroll
      for (int j = 0; j < 8; ++j) w[j] = (short)f2bf(src[j]);
      *(v8b*)&Wlds[(kb * 32 + r) * 8] = w;
    }
    __syncthreads();
    float bias[2];
#pragma unroll
    for (int nt = 0; nt < 2; ++nt) bias[nt] = b1[rbase + nt * 16 + m16];
    for (int t = 0; t < TT; ++t) {
      wait_set(fL0 + t * NL0, NL0);
      if (t >= 4) wait_set(fL1 + (t - 4) * NL1, NL1);  // xp1 ring back-pressure
      __syncthreads();
      const u16* hp = h0r + (t & 3) * (BB * HH) + bm * HH + q * 8;
      v4f acc0 = {0.f,0.f,0.f,0.f}, acc1 = {0.f,0.f,0.f,0.f};
#pragma unroll 4
      for (int k0 = 0; k0 < HH; k0 += 32) {
        v8b a = ldg16_b(hp + k0);
        v8b w0 = *(const v8b*)&Wlds[(((k0 >> 3) + q) * 32 + m16) * 8];
        v8b w1 = *(const v8b*)&Wlds[(((k0 >> 3) + q) * 32 + 16 + m16) * 8];
        acc0 = __builtin_amdgcn_mfma_f32_16x16x32_bf16(a, w0, acc0, 0, 0, 0);
        acc1 = __builtin_amdgcn_mfma_f32_16x16x32_bf16(a, w1, acc1, 0, 0, 0);
      }
      const int slot = t & 3;
      v4f v0 = acc0 + bias[0];
      v4f v1 = acc1 + bias[1];
      stg16_f(&xp1[(long)slot * (GG * BB) + (long)(rbase + m16) * BB + bq], v0);
      stg16_f(&xp1[(long)slot * (GG * BB) + (long)(rbase + 16 + m16) * BB + bq], v1);
      drain_stores();
      __syncthreads();
      set_flag(&fA1[t * NA1 + awg]);
    }
  } else {
    // ================= L1: gates = xp1 + W_hh1 @ h1[t-1]; cell + last-step capture ============
    const int uwg = wg - (NA0 + NL0 + NA1);
    const int ubase = uwg * 8;
    for (int c2 = tid; c2 < 32 * 128; c2 += 256) {
      int r = c2 >> 7, kb = c2 & 127;
      int grow = (r >> 3) * HH + ubase + (r & 7);
      const float* src = Whh1 + (long)grow * HH + kb * 8;
      v8b w;
#pragma unroll
      for (int j = 0; j < 8; ++j) w[j] = (short)f2bf(src[j]);
      *(v8b*)&Wlds[(kb * 32 + r) * 8] = w;
    }
    __syncthreads();
    const int gi0 = (m16 >> 3);
    const int j0 = m16 & 7;
    const int row0 = gi0 * HH + ubase + j0;
    const int row1 = (2 + gi0) * HH + ubase + j0;
    const bool lo = (m16 < 8);
    float cst[4] = {0.f, 0.f, 0.f, 0.f};
    int len4[4];
#pragma unroll
    for (int r = 0; r < 4; ++r) len4[r] = lens[bq + r];
    for (int t = 0; t < TT; ++t) {
      wait_set(fA1 + t * NA1, NA1);
      if (t >= 1) wait_set(fL1 + (t - 1) * NL1, NL1);
      __syncthreads();
      const float* xpS = xp1 + (long)(t & 3) * (GG * BB);
      v4f x0 = ldg16_f(&xpS[(long)row0 * BB + bq]);
      v4f x1 = ldg16_f(&xpS[(long)row1 * BB + bq]);
      const u16* hp = h1r + ((t + 3) & 3) * (BB * HH) + bm * HH + q * 8;
      v4f acc0 = {0.f,0.f,0.f,0.f}, acc1 = {0.f,0.f,0.f,0.f};
#pragma unroll 4
      for (int k0 = 0; k0 < HH; k0 += 32) {
        v8b a = ldg16_b(hp + k0);
        v8b w0 = *(const v8b*)&Wlds[(((k0 >> 3) + q) * 32 + m16) * 8];
        v8b w1 = *(const v8b*)&Wlds[(((k0 >> 3) + q) * 32 + 16 + m16) * 8];
        acc0 = __builtin_amdgcn_mfma_f32_16x16x32_bf16(a, w0, acc0, 0, 0, 0);
        acc1 = __builtin_amdgcn_mfma_f32_16x16x32_bf16(a, w1, acc1, 0, 0, 0);
      }
      acc0 += x0; acc1 += x1;
      u16* hw = h1r + (t & 3) * (BB * HH);
#pragma unroll
      for (int r = 0; r < 4; ++r) {
        float a0 = acc0[r], a1 = acc1[r];
        float p0 = __shfl_xor(a0, 8, 64);
        float p1 = __shfl_xor(a1, 8, 64);
        float iv = lo ? a0 : p0;
        float fv = lo ? p0 : a0;
        float gv = lo ? a1 : p1;
        float ov = lo ? p1 : a1;
        float cn = sigm(fv) * cst[r] + sigm(iv) * tanhf(gv);
        cst[r] = cn;
        float hv = sigm(ov) * tanhf(cn);
        if (lo) {
          stg2_h(&hw[(bq + r) * HH + ubase + j0], f2bf(hv));
          if (t == len4[r] - 1) lasth[(long)(bq + r) * HH + ubase + j0] = hv;
        }
      }
      drain_stores();
      __syncthreads();
      set_flag(&fL1[t * NL1 + uwg]);
    }
  }
}

// ---------------- final: out = last_h1 @ W_out^T + b_out (all fp32) ----------------
__global__ void out_kernel(const float* __restrict__ lasth, const float* __restrict__ Wout,
                           const float* __restrict__ bout, float* __restrict__ out) {
  int b = blockIdx.x;
  int k = threadIdx.x;
  if (k < 10) {
    float acc = bout[k];
    const float* hb = lasth + (long)b * HH;
    const float* wr = Wout + (long)k * HH;
    for (int j = 0; j < HH; ++j) acc += hb[j] * wr[j];
    out[b * 10 + k] = acc;
  }
}

extern "C" void kernel_launch(void* const* d_in, const int* in_sizes, int n_in,
                              void* d_out, int out_size, void* d_ws, size_t ws_size,
                              hipStream_t stream) {
  const int*   x    = (const int*)d_in[0];
  const float* emb  = (const float*)d_in[1];
  const float* Wih0 = (const float*)d_in[2];
  const float* Whh0 = (const float*)d_in[3];
  const float* b0   = (const float*)d_in[4];
  const float* Wih1 = (const float*)d_in[5];
  const float* Whh1 = (const float*)d_in[6];
  const float* b1   = (const float*)d_in[7];
  const float* Wout = (const float*)d_in[8];
  const float* bout = (const float*)d_in[9];

  char* ws = (char*)d_ws;
  u16*   e16   = (u16*)(ws + 0);            // 33,554,432 B
  float* xp0   = (float*)(ws + 33554432);   // 8 slots * 4096 * 64 * 4 = 8,388,608 B
  float* xp1   = (float*)(ws + 41943040);   // 4 slots * 4096 * 64 * 4 = 4,194,304 B
  u16*   h0r   = (u16*)(ws + 46137344);     // 4 slots * 64 * 1024 * 2 =   524,288 B
  u16*   h1r   = (u16*)(ws + 46661632);     //   524,288 B
  float* lasth = (float*)(ws + 47185920);   //   262,144 B
  int*   lens  = (int*)(ws + 47448064);     //       256 B
  u32*   flags = (u32*)(ws + 47448320);     //   917,504 B  (total ~46.2 MB)
  u32* fA0 = flags;
  u32* fL0 = fA0 + 512 * NA0;
  u32* fA1 = fL0 + 512 * NL0;
  u32* fL1 = fA1 + 512 * NA1;
  int flag_u32s = 512 * NA0 + 512 * NL0 + 512 * NA1 + 512 * NL1;

  prep_kernel<<<2048, 256, 0, stream>>>(x, emb, e16, h0r, h1r, lens, flags, flag_u32s);
  lstm_persist<<<NWG, 256, 0, stream>>>(e16, Wih0, Whh0, b0, Wih1, Whh1, b1, lens,
                                        xp0, xp1, h0r, h1r, lasth, fA0, fL0, fA1, fL1);
  out_kernel<<<BB, 64, 0, stream>>>(lasth, Wout, bout, (float*)d_out);
}